// Round 6
// baseline (242.229 us; speedup 1.0000x reference)
//
#include <hip/hip_runtime.h>

#define N_NODES 100000
#define N_EDGES 600000
#define NT2 9375    // edge tiles of 64 (600000 = 9375*64 exactly)
#define LDW 264     // raw-tile row stride (f16): 256 data cols + 8 pad
#define LDH 136     // h1-tile row stride (f16): 128 data cols + 8 pad
typedef _Float16 f16x8 __attribute__((ext_vector_type(8)));
typedef __attribute__((ext_vector_type(4))) float f32x4;

__device__ __forceinline__ float elu_f(float v) {
    return v > 0.0f ? v : (__expf(v) - 1.0f);
}

// k0: (a) x f32 -> f16 gather table (streaming, ~77MB); (b) first 16 blocks
// also build W1f (W1 in MFMA-fragment order, 64KB, L2-hot in k2).
// Frag id = (w4*16 + half*8 + c*4 + ks)*64 + lane, col = w4*32+c*16+ln.
extern "C" __global__ __launch_bounds__(256)
void k0_convert(const float* __restrict__ x, const float* __restrict__ W1,
                _Float16* __restrict__ xh, _Float16* __restrict__ W1f) {
    const int t = threadIdx.x;
    if (blockIdx.x < 16) {
        const int id = blockIdx.x * 256 + t;   // 0..4095
        const int lane = id & 63, f = id >> 6;
        const int ks = f & 3, c = (f >> 2) & 1, half = (f >> 3) & 1, w4 = f >> 4;
        const int ln = lane & 15, kg = lane >> 4;
        const int col = w4 * 32 + c * 16 + ln;
        f16x8 v;
#pragma unroll
        for (int j = 0; j < 8; ++j)
            v[j] = (_Float16)W1[(half * 128 + ks * 32 + kg * 8 + j) * 128 + col];
        *(f16x8*)(W1f + (size_t)id * 8) = v;
    }
    const int step = gridDim.x * blockDim.x;
    for (int c = blockIdx.x * blockDim.x + t; c < (N_NODES * 128) / 8; c += step) {
        const float4 a0 = *(const float4*)(x + (size_t)c * 8);
        const float4 a1 = *(const float4*)(x + (size_t)c * 8 + 4);
        f16x8 h;
        h[0] = (_Float16)a0.x; h[1] = (_Float16)a0.y;
        h[2] = (_Float16)a0.z; h[3] = (_Float16)a0.w;
        h[4] = (_Float16)a1.x; h[5] = (_Float16)a1.y;
        h[6] = (_Float16)a1.z; h[7] = (_Float16)a1.w;
        *(f16x8*)(xh + (size_t)c * 8) = h;
    }
}

// k2 fused v4: 512-thread blocks, 2/CU. Gather path is LATENCY-bound (fill
// rate tracked concurrency in rounds 0-5: 1.73 TB/s @12 waves, 2.83 @16w-
// thrashed, 1.11 @12w+longer pipeline). 8 waves/tile (16-col strip each,
// c-loop collapsed) gives 16 waves/CU at only 64 blocks/XCD (safe L2 side),
// halves per-thread LDS scalar stores, and keeps VGPR ~95 < 128 cap.
// Schedule per tile (2 barriers, proven in r4/r5):
//   [gather nt -> regs | layer-1 MFMA on sRaw] B1
//   [out-write prev | h1 -> sH1 | regs -> sRaw] B2
//   [layer-2 MFMA on sH1 + reduce -> sPart]
extern "C" __global__ __launch_bounds__(512, 2)
void k2_edge_mlp(const _Float16* __restrict__ xh, const void* __restrict__ eiv,
                 const _Float16* __restrict__ W1f, const float* __restrict__ b1,
                 const float* __restrict__ W2, const float* __restrict__ b2,
                 const float* __restrict__ W3, const float* __restrict__ b3,
                 float* __restrict__ out) {
    __shared__ __align__(16) _Float16 sRaw[64 * LDW];  // 33.8 KB
    __shared__ __align__(16) _Float16 sH1[64 * LDH];   // 17.4 KB
    __shared__ float sPart[8][64];                     // 2 KB
    __shared__ int sFlag;

    const int t = threadIdx.x;
    const int w = t >> 6, lane = t & 63;   // 8 waves
    const int ln = lane & 15, kg = lane >> 4;
    const int row_s = t >> 3;        // staging row 0..63
    const int qb = (t & 7) * 16;     // staging 16-f16 (32B) chunk base
    const float b3v = b3[0];
    const int stride = gridDim.x;

    if (t < 64) {
        unsigned v = ((const unsigned*)eiv)[2 * t + 1];
        unsigned long long bm = __ballot(v == 0u);
        if (t == 0) sFlag = (bm == ~0ull) ? 1 : 0;
    }

    // This wave's W1f slice: cols w*16..w*16+16 => legacy (w4 = w>>1, c = w&1).
    const _Float16* w1w = W1f + (size_t)((w >> 1) * 16 + (w & 1) * 4) * 512;

    // Layer-2 B-frags: resident, 16 VGPR (single 16-col strip).
    f16x8 bf2[4];
    {
        const int n = w * 16 + ln;
#pragma unroll
        for (int ks = 0; ks < 4; ++ks) {
            f16x8 v;
#pragma unroll
            for (int j = 0; j < 8; ++j) {
                int k = ks * 32 + kg * 8 + j;
                v[j] = (_Float16)W2[k * 128 + n];
            }
            bf2[ks] = v;
        }
    }

    const int coln = w * 16 + ln;
    const float b1v = b1[coln], b2v = b2[coln], w3v = W3[coln];

    __syncthreads();
    const int mode64 = sFlag;
    const int tile0 = blockIdx.x;   // 512 <= NT2 always

    int se_nx, ge_nx;
    // Prologue: stage tile0 into sRaw.
    {
        int e = tile0 * 64 + row_s;
        int se, ge;
        if (mode64) {
            se = (int)((const long long*)eiv)[e];
            ge = (int)((const long long*)eiv)[N_EDGES + e];
        } else {
            se = ((const int*)eiv)[e];
            ge = ((const int*)eiv)[N_EDGES + e];
        }
        const _Float16* pa = xh + (size_t)se * 128 + qb;
        const _Float16* pb = xh + (size_t)ge * 128 + qb;
#pragma unroll
        for (int i = 0; i < 2; ++i) {
            f16x8 ga = *(const f16x8*)(pa + i * 8);
            f16x8 gb = *(const f16x8*)(pb + i * 8);
            *(f16x8*)(&sRaw[row_s * LDW + qb + i * 8]) = ga;
            *(f16x8*)(&sRaw[row_s * LDW + 128 + qb + i * 8]) = gb;
        }
    }
    {
        int t1 = tile0 + stride;
        int t1c = (t1 < NT2) ? t1 : tile0;
        int e = t1c * 64 + row_s;
        if (mode64) {
            se_nx = (int)((const long long*)eiv)[e];
            ge_nx = (int)((const long long*)eiv)[N_EDGES + e];
        } else {
            se_nx = ((const int*)eiv)[e];
            ge_nx = ((const int*)eiv)[N_EDGES + e];
        }
    }
    __syncthreads();   // sRaw ready

    int prevE0 = -1;
    for (int tile = tile0; tile < NT2; tile += stride) {
        const int nt = tile + stride;
        const int ntc = (nt < NT2) ? nt : tile;

        // (1) Issue gathers for tile nt; held in regs across layer-1.
        const _Float16* pa = xh + (size_t)se_nx * 128 + qb;
        const _Float16* pb = xh + (size_t)ge_nx * 128 + qb;
        f16x8 Ga[2], Gb[2];
#pragma unroll
        for (int i = 0; i < 2; ++i) {
            Ga[i] = *(const f16x8*)(pa + i * 8);
            Gb[i] = *(const f16x8*)(pb + i * 8);
        }

        // (1b) Indices for tile nt+stride.
        {
            int n2 = nt + stride;
            int n2c = (n2 < NT2) ? n2 : ntc;
            int e = n2c * 64 + row_s;
            if (mode64) {
                se_nx = (int)((const long long*)eiv)[e];
                ge_nx = (int)((const long long*)eiv)[N_EDGES + e];
            } else {
                se_nx = ((const int*)eiv)[e];
                ge_nx = ((const int*)eiv)[N_EDGES + e];
            }
        }

        // (2) Layer 1: h1 = src.W1a + tgt.W1b. W1 frags streamed (L2-hot,
        //     unroll 1 keeps only 2 frags = 8 VGPR live).
        f32x4 acc1[4];
#pragma unroll
        for (int rt = 0; rt < 4; ++rt) acc1[rt] = (f32x4){0.f, 0.f, 0.f, 0.f};

#pragma unroll 1
        for (int ks = 0; ks < 4; ++ks) {
            f16x8 w1f[2];
#pragma unroll
            for (int half = 0; half < 2; ++half)
                w1f[half] = *(const f16x8*)(
                    w1w + ((half * 8 + ks) * 64 + lane) * 8);
#pragma unroll
            for (int rt = 0; rt < 4; ++rt) {
                f16x8 a_s = *(const f16x8*)(&sRaw[(rt * 16 + ln) * LDW + ks * 32 + kg * 8]);
                f16x8 a_t = *(const f16x8*)(&sRaw[(rt * 16 + ln) * LDW + 128 + ks * 32 + kg * 8]);
                acc1[rt] = __builtin_amdgcn_mfma_f32_16x16x32_f16(
                    a_s, w1f[0], acc1[rt], 0, 0, 0);
                acc1[rt] = __builtin_amdgcn_mfma_f32_16x16x32_f16(
                    a_t, w1f[1], acc1[rt], 0, 0, 0);
            }
        }
        __syncthreads();   // B1: layer-1 reads of sRaw done; sPart(prev) ready

        // (3a) Out-write for the previous tile (overlaps LDS writes below).
        if (prevE0 >= 0 && t < 64) {
            float s = b3v;
#pragma unroll
            for (int ww = 0; ww < 8; ++ww) s += sPart[ww][t];
            out[prevE0 + t] = s;
        }

        // (3b) elu -> h1 (f16) into sH1 (C-layout [m89/m91]).
#pragma unroll
        for (int rt = 0; rt < 4; ++rt)
#pragma unroll
            for (int reg = 0; reg < 4; ++reg) {
                const int row = rt * 16 + kg * 4 + reg;
                sH1[row * LDH + coln] = (_Float16)elu_f(acc1[rt][reg] + b1v);
            }

        // (3c) Stage gathered tile nt -> sRaw (reads done at B1).
#pragma unroll
        for (int i = 0; i < 2; ++i) {
            *(f16x8*)(&sRaw[row_s * LDW + qb + i * 8]) = Ga[i];
            *(f16x8*)(&sRaw[row_s * LDW + 128 + qb + i * 8]) = Gb[i];
        }
        __syncthreads();   // B2: sH1 + sRaw(next) ready

        // (4) Layer 2 + fused layer 3 reduce -> sPart.
        f32x4 acc2[4];
#pragma unroll
        for (int rt = 0; rt < 4; ++rt) acc2[rt] = (f32x4){0.f, 0.f, 0.f, 0.f};

#pragma unroll
        for (int ks = 0; ks < 4; ++ks) {
#pragma unroll
            for (int rt = 0; rt < 4; ++rt) {
                f16x8 a = *(const f16x8*)(&sH1[(rt * 16 + ln) * LDH + ks * 32 + kg * 8]);
                acc2[rt] = __builtin_amdgcn_mfma_f32_16x16x32_f16(
                    a, bf2[ks], acc2[rt], 0, 0, 0);
            }
        }

#pragma unroll
        for (int rt = 0; rt < 4; ++rt) {
            float pr[4];
#pragma unroll
            for (int reg = 0; reg < 4; ++reg)
                pr[reg] = elu_f(acc2[rt][reg] + b2v) * w3v;
#pragma unroll
            for (int m = 1; m < 16; m <<= 1)
#pragma unroll
                for (int reg = 0; reg < 4; ++reg) pr[reg] += __shfl_xor(pr[reg], m, 64);
            if (ln == 0) {
#pragma unroll
                for (int reg = 0; reg < 4; ++reg)
                    sPart[w][rt * 16 + kg * 4 + reg] = pr[reg];
            }
        }
        // No barrier: next iter's B1 orders sPart writes vs out-read, and
        // layer-1 only READS sRaw (fully written before B2).

        prevE0 = tile * 64;
    }

    __syncthreads();   // final sPart ready
    if (prevE0 >= 0 && t < 64) {
        float s = b3v;
#pragma unroll
        for (int ww = 0; ww < 8; ++ww) s += sPart[ww][t];
        out[prevE0 + t] = s;
    }
}

extern "C" void kernel_launch(void* const* d_in, const int* in_sizes, int n_in,
                              void* d_out, int out_size, void* d_ws, size_t ws_size,
                              hipStream_t stream) {
    const float* x  = (const float*)d_in[0];
    const void*  ei = d_in[1];
    const float* W1 = (const float*)d_in[2];
    const float* b1 = (const float*)d_in[3];
    const float* W2 = (const float*)d_in[4];
    const float* b2 = (const float*)d_in[5];
    const float* W3 = (const float*)d_in[6];
    const float* b3 = (const float*)d_in[7];
    float* out = (float*)d_out;

    _Float16* xh  = (_Float16*)((char*)d_ws + 256);          // 25.6 MB
    _Float16* W1f = xh + (size_t)N_NODES * 128;              // 64 KB

    k0_convert<<<2048, 256, 0, stream>>>(x, W1, xh, W1f);
    k2_edge_mlp<<<512, 512, 0, stream>>>(xh, ei, W1f, b1, W2, b2, W3, b3, out);
}

// Round 7
// 237.668 us; speedup vs baseline: 1.0192x; 1.0192x over previous
//
#include <hip/hip_runtime.h>

#define N_NODES 100000
#define N_EDGES 600000
#define NT2 9375    // edge tiles of 64 (600000 = 9375*64 exactly)
#define LDW 264     // raw-tile row stride (f16): 256 data cols + 8 pad
#define LDH 136     // h1-tile row stride (f16): 128 data cols + 8 pad
typedef _Float16 f16x8 __attribute__((ext_vector_type(8)));
typedef __attribute__((ext_vector_type(4))) float f32x4;

__device__ __forceinline__ float elu_f(float v) {
    return v > 0.0f ? v : (__expf(v) - 1.0f);
}

// k0: x f32 -> f16 gather table. Pure streaming, ~77MB.
extern "C" __global__ __launch_bounds__(256)
void k0_convert(const float* __restrict__ x, _Float16* __restrict__ xh) {
    const int step = gridDim.x * blockDim.x;
    for (int c = blockIdx.x * blockDim.x + threadIdx.x; c < (N_NODES * 128) / 8;
         c += step) {
        const float4 a0 = *(const float4*)(x + (size_t)c * 8);
        const float4 a1 = *(const float4*)(x + (size_t)c * 8 + 4);
        f16x8 h;
        h[0] = (_Float16)a0.x; h[1] = (_Float16)a0.y;
        h[2] = (_Float16)a0.z; h[3] = (_Float16)a0.w;
        h[4] = (_Float16)a1.x; h[5] = (_Float16)a1.y;
        h[6] = (_Float16)a1.z; h[7] = (_Float16)a1.w;
        *(f16x8*)(xh + (size_t)c * 8) = h;
    }
}

// k2 fused v5. r6's diagnosis: W1f loads INSIDE layer-1 + in-order vmcnt =
// every tile's compute phase drains the gather prefetch (vmcnt waits for the
// W1f frag must complete all OLDER loads = the random gathers). Fix:
//  (a) bf1 fully RESIDENT (512-thr/16-col strips make bf1=32+bf2=16 VGPR fit
//      under the 128 cap) -> compute phase has ZERO vmem -> gathers stay
//      outstanding across the whole tile.
//  (b) 2-deep gather pipeline: at iter t issue gathers for t+2 (buf B) while
//      buf A (t+1) is consumed at staging. Consume order = issue order, so
//      the vmcnt wait for A leaves B in flight. 8 loads/thread outstanding.
// Schedule per tile (2 barriers, proven r4-r6):
//   [issue gathers t+2 | idx t+3 | layer-1 MFMA (reg-only)] B1
//   [out prev | h1 -> sH1 | bufA -> sRaw] B2
//   [layer-2 MFMA + reduce -> sPart | rotate bufs]
extern "C" __global__ __launch_bounds__(512, 4)
void k2_edge_mlp(const _Float16* __restrict__ xh, const void* __restrict__ eiv,
                 const float* __restrict__ W1, const float* __restrict__ b1,
                 const float* __restrict__ W2, const float* __restrict__ b2,
                 const float* __restrict__ W3, const float* __restrict__ b3,
                 float* __restrict__ out) {
    __shared__ __align__(16) _Float16 sRaw[64 * LDW];  // 33.8 KB
    __shared__ __align__(16) _Float16 sH1[64 * LDH];   // 17.4 KB
    __shared__ float sPart[8][64];                     // 2 KB
    __shared__ int sFlag;

    const int t = threadIdx.x;
    const int w = t >> 6, lane = t & 63;   // 8 waves
    const int ln = lane & 15, kg = lane >> 4;
    const int row_s = t >> 3;        // staging row 0..63
    const int qb = (t & 7) * 16;     // staging 16-f16 (32B) chunk base
    const float b3v = b3[0];
    const int stride = gridDim.x;

    if (t < 64) {
        unsigned v = ((const unsigned*)eiv)[2 * t + 1];
        unsigned long long bm = __ballot(v == 0u);
        if (t == 0) sFlag = (bm == ~0ull) ? 1 : 0;
    }

    const int coln = w * 16 + ln;

    // Layer-1 B-frags RESIDENT: both W1 k-halves, 16-col strip. 32 VGPR.
    f16x8 bf1[2][4];
#pragma unroll
    for (int half = 0; half < 2; ++half)
#pragma unroll
        for (int ks = 0; ks < 4; ++ks) {
            f16x8 v;
#pragma unroll
            for (int j = 0; j < 8; ++j) {
                int k = half * 128 + ks * 32 + kg * 8 + j;
                v[j] = (_Float16)W1[k * 128 + coln];
            }
            bf1[half][ks] = v;
        }

    // Layer-2 B-frags RESIDENT: 16 VGPR.
    f16x8 bf2[4];
#pragma unroll
    for (int ks = 0; ks < 4; ++ks) {
        f16x8 v;
#pragma unroll
        for (int j = 0; j < 8; ++j) {
            int k = ks * 32 + kg * 8 + j;
            v[j] = (_Float16)W2[k * 128 + coln];
        }
        bf2[ks] = v;
    }

    const float b1v = b1[coln], b2v = b2[coln], w3v = W3[coln];

    __syncthreads();
    const int mode64 = sFlag;
    const int tile0 = blockIdx.x;   // 512 <= NT2 always

#define LOAD_IDX(TT, SE, GE) do {                                   \
        int e_ = (TT) * 64 + row_s;                                 \
        if (mode64) {                                               \
            SE = (int)((const long long*)eiv)[e_];                  \
            GE = (int)((const long long*)eiv)[N_EDGES + e_];        \
        } else {                                                    \
            SE = ((const int*)eiv)[e_];                             \
            GE = ((const int*)eiv)[N_EDGES + e_];                   \
        }                                                           \
    } while (0)

    // Prologue: stage tile0 -> sRaw; issue gathers for tile0+s -> bufA;
    // load indices for tile0+2s.
    {
        int se, ge;
        LOAD_IDX(tile0, se, ge);
        const _Float16* pa = xh + (size_t)se * 128 + qb;
        const _Float16* pb = xh + (size_t)ge * 128 + qb;
#pragma unroll
        for (int i = 0; i < 2; ++i) {
            f16x8 ga = *(const f16x8*)(pa + i * 8);
            f16x8 gb = *(const f16x8*)(pb + i * 8);
            *(f16x8*)(&sRaw[row_s * LDW + qb + i * 8]) = ga;
            *(f16x8*)(&sRaw[row_s * LDW + 128 + qb + i * 8]) = gb;
        }
    }
    f16x8 GaA[2], GbA[2];
    {
        int t1 = tile0 + stride;
        int t1c = (t1 < NT2) ? t1 : tile0;
        int se, ge;
        LOAD_IDX(t1c, se, ge);
        const _Float16* pa = xh + (size_t)se * 128 + qb;
        const _Float16* pb = xh + (size_t)ge * 128 + qb;
#pragma unroll
        for (int i = 0; i < 2; ++i) {
            GaA[i] = *(const f16x8*)(pa + i * 8);
            GbA[i] = *(const f16x8*)(pb + i * 8);
        }
    }
    int se2, ge2;
    {
        int t2 = tile0 + 2 * stride;
        int t2c = (t2 < NT2) ? t2 : tile0;
        LOAD_IDX(t2c, se2, ge2);
    }
    __syncthreads();   // sRaw ready

    int prevE0 = -1;
    for (int tile = tile0; tile < NT2; tile += stride) {
        // (1) Issue gathers for tile+2*stride -> bufB (stays outstanding
        //     through this tile AND next tile's layer-1).
        f16x8 GaB[2], GbB[2];
        {
            const _Float16* pa = xh + (size_t)se2 * 128 + qb;
            const _Float16* pb = xh + (size_t)ge2 * 128 + qb;
#pragma unroll
            for (int i = 0; i < 2; ++i) {
                GaB[i] = *(const f16x8*)(pa + i * 8);
                GbB[i] = *(const f16x8*)(pb + i * 8);
            }
        }
        // (1b) Indices for tile+3*stride.
        {
            int t3 = tile + 3 * stride;
            int t3c = (t3 < NT2) ? t3 : tile;
            LOAD_IDX(t3c, se2, ge2);
        }

        // (2) Layer 1: h1 = src.W1a + tgt.W1b — register-only operands,
        //     NO vmem in this phase (gathers keep flying).
        f32x4 acc1[4];
#pragma unroll
        for (int rt = 0; rt < 4; ++rt) acc1[rt] = (f32x4){0.f, 0.f, 0.f, 0.f};

#pragma unroll
        for (int ks = 0; ks < 4; ++ks) {
#pragma unroll
            for (int rt = 0; rt < 4; ++rt) {
                f16x8 a_s = *(const f16x8*)(&sRaw[(rt * 16 + ln) * LDW + ks * 32 + kg * 8]);
                f16x8 a_t = *(const f16x8*)(&sRaw[(rt * 16 + ln) * LDW + 128 + ks * 32 + kg * 8]);
                acc1[rt] = __builtin_amdgcn_mfma_f32_16x16x32_f16(
                    a_s, bf1[0][ks], acc1[rt], 0, 0, 0);
                acc1[rt] = __builtin_amdgcn_mfma_f32_16x16x32_f16(
                    a_t, bf1[1][ks], acc1[rt], 0, 0, 0);
            }
        }
        __syncthreads();   // B1: layer-1 reads of sRaw done; sPart(prev) ready

        // (3a) Out-write for the previous tile.
        if (prevE0 >= 0 && t < 64) {
            float s = b3v;
#pragma unroll
            for (int ww = 0; ww < 8; ++ww) s += sPart[ww][t];
            out[prevE0 + t] = s;
        }

        // (3b) elu -> h1 (f16) into sH1 (C-layout [m89/m91]).
#pragma unroll
        for (int rt = 0; rt < 4; ++rt)
#pragma unroll
            for (int reg = 0; reg < 4; ++reg) {
                const int row = rt * 16 + kg * 4 + reg;
                sH1[row * LDH + coln] = (_Float16)elu_f(acc1[rt][reg] + b1v);
            }

        // (3c) Stage bufA (tile+1) -> sRaw. vmcnt wait here drains only the
        //     OLDEST loads (bufA, issued last iter); bufB stays in flight.
#pragma unroll
        for (int i = 0; i < 2; ++i) {
            *(f16x8*)(&sRaw[row_s * LDW + qb + i * 8]) = GaA[i];
            *(f16x8*)(&sRaw[row_s * LDW + 128 + qb + i * 8]) = GbA[i];
        }
        __syncthreads();   // B2: sH1 + sRaw(next) ready

        // (4) Layer 2 + fused layer 3 reduce -> sPart.
        f32x4 acc2[4];
#pragma unroll
        for (int rt = 0; rt < 4; ++rt) acc2[rt] = (f32x4){0.f, 0.f, 0.f, 0.f};

#pragma unroll
        for (int ks = 0; ks < 4; ++ks) {
#pragma unroll
            for (int rt = 0; rt < 4; ++rt) {
                f16x8 a = *(const f16x8*)(&sH1[(rt * 16 + ln) * LDH + ks * 32 + kg * 8]);
                acc2[rt] = __builtin_amdgcn_mfma_f32_16x16x32_f16(
                    a, bf2[ks], acc2[rt], 0, 0, 0);
            }
        }

#pragma unroll
        for (int rt = 0; rt < 4; ++rt) {
            float pr[4];
#pragma unroll
            for (int reg = 0; reg < 4; ++reg)
                pr[reg] = elu_f(acc2[rt][reg] + b2v) * w3v;
#pragma unroll
            for (int m = 1; m < 16; m <<= 1)
#pragma unroll
                for (int reg = 0; reg < 4; ++reg) pr[reg] += __shfl_xor(pr[reg], m, 64);
            if (ln == 0) {
#pragma unroll
                for (int reg = 0; reg < 4; ++reg)
                    sPart[w][rt * 16 + kg * 4 + reg] = pr[reg];
            }
        }

        // (5) Rotate gather buffers (B -> A).
#pragma unroll
        for (int i = 0; i < 2; ++i) {
            GaA[i] = GaB[i];
            GbA[i] = GbB[i];
        }
        // No barrier: next iter's B1 orders sPart writes vs out-read, and
        // layer-1 only READS sRaw (fully written before B2).

        prevE0 = tile * 64;
    }

    __syncthreads();   // final sPart ready
    if (prevE0 >= 0 && t < 64) {
        float s = b3v;
#pragma unroll
        for (int ww = 0; ww < 8; ++ww) s += sPart[ww][t];
        out[prevE0 + t] = s;
    }
#undef LOAD_IDX
}

extern "C" void kernel_launch(void* const* d_in, const int* in_sizes, int n_in,
                              void* d_out, int out_size, void* d_ws, size_t ws_size,
                              hipStream_t stream) {
    const float* x  = (const float*)d_in[0];
    const void*  ei = d_in[1];
    const float* W1 = (const float*)d_in[2];
    const float* b1 = (const float*)d_in[3];
    const float* W2 = (const float*)d_in[4];
    const float* b2 = (const float*)d_in[5];
    const float* W3 = (const float*)d_in[6];
    const float* b3 = (const float*)d_in[7];
    float* out = (float*)d_out;

    _Float16* xh = (_Float16*)((char*)d_ws + 256);  // 100000*128 f16 = 25.6 MB

    k0_convert<<<2048, 256, 0, stream>>>(x, xh);
    k2_edge_mlp<<<512, 512, 0, stream>>>(xh, ei, W1, b1, W2, b2, W3, b3, out);
}

// Round 8
// 192.078 us; speedup vs baseline: 1.2611x; 1.2374x over previous
//
#include <hip/hip_runtime.h>

#define N_NODES 100000
#define N_EDGES 600000
#define NT1 1563    // k1 node tiles of 64
#define NT2 9375    // k2 edge tiles of 64 (600000 = 9375*64 exactly)
#define LDH 136     // padded row stride (f16 elems), 16B-aligned rows
typedef _Float16 f16x8 __attribute__((ext_vector_type(8)));
typedef __attribute__((ext_vector_type(4))) float f32x4;

__device__ __forceinline__ float elu_f(float v) {
    return v > 0.0f ? v : (__expf(v) - 1.0f);
}

// k0: build W1f = W1 in MFMA-fragment order (64 frags x 64 lanes x 8 f16 =
// 64KB). One-time strided gather by 16 blocks (trivial), so k1 can load its
// fragment set with 32 PERFECTLY COALESCED dwordx4 per thread instead of 256
// strided scalar loads. The strided per-block preload was the k1-family's
// hidden floor: 64 distinct lines per wave-instruction -> ~50M TA/L2
// transactions across the grid to read a 128KB matrix (r1/r2/r0 k1 variants
// all ~110-140us regardless of staging/epilogue -> the shared fragload).
// Frag id = (w*16 + half*8 + c*4 + ks)*64 + lane; col = w*32+c*16+ln;
// k = half*128 + ks*32 + kg*8 + j.  [builder verbatim from r5, passed]
extern "C" __global__ __launch_bounds__(256)
void k0_w1f(const float* __restrict__ W1, _Float16* __restrict__ W1f) {
    const int t = threadIdx.x;
    const int id = blockIdx.x * 256 + t;   // 0..4095
    const int lane = id & 63, f = id >> 6;
    const int ks = f & 3, c = (f >> 2) & 1, half = (f >> 3) & 1, w = f >> 4;
    const int ln = lane & 15, kg = lane >> 4;
    const int col = w * 32 + c * 16 + ln;
    f16x8 v;
#pragma unroll
    for (int j = 0; j < 8; ++j)
        v[j] = (_Float16)W1[(half * 128 + ks * 32 + kg * 8 + j) * 128 + col];
    *(f16x8*)(W1f + (size_t)id * 8) = v;
}

// k1: round-0 body UNCHANGED except the W1 fragment preload now reads W1f
// coalesced (16B/lane, 1KB dense per wave instruction, W1f L2-resident).
extern "C" __global__ __launch_bounds__(256, 3)
void k1_node_linear(const float* __restrict__ x, const _Float16* __restrict__ W1f,
                    _Float16* __restrict__ P) {
    __shared__ __align__(16) _Float16 sX[64 * LDH];   // 17.4 KB

    const int t = threadIdx.x;
    const int w = t >> 6, lane = t & 63;
    const int ln = lane & 15, kg = lane >> 4;
    const int le = t >> 2;        // staging/store row 0..63
    const int q  = t & 3;         // 32-col chunk 0..3

    // W1 fragments, both halves, this wave's 32-col strip: 64 VGPR,
    // loaded once per block via 32 coalesced dwordx4.
    f16x8 bf[2][2][4];
#pragma unroll
    for (int half = 0; half < 2; ++half)
#pragma unroll
        for (int c = 0; c < 2; ++c)
#pragma unroll
            for (int ks = 0; ks < 4; ++ks)
                bf[half][c][ks] = *(const f16x8*)(
                    W1f + (size_t)((w * 16 + half * 8 + c * 4 + ks) * 64 + lane) * 8);

    for (int tile = blockIdx.x; tile < NT1; tile += gridDim.x) {
        const int n0 = tile * 64;
        __syncthreads();   // previous tile's epilogue reads of sX done

        // Stage x tile as f16 (single read of x).
        {
            int n = n0 + le;
#pragma unroll
            for (int i = 0; i < 4; ++i) {
                float4 a0 = make_float4(0.f, 0.f, 0.f, 0.f), a1 = a0;
                if (n < N_NODES) {
                    const float* p = x + (size_t)n * 128 + q * 32 + i * 8;
                    a0 = *(const float4*)p; a1 = *(const float4*)(p + 4);
                }
                f16x8 vh;
                vh[0] = (_Float16)a0.x; vh[1] = (_Float16)a0.y;
                vh[2] = (_Float16)a0.z; vh[3] = (_Float16)a0.w;
                vh[4] = (_Float16)a1.x; vh[5] = (_Float16)a1.y;
                vh[6] = (_Float16)a1.z; vh[7] = (_Float16)a1.w;
                *(f16x8*)(&sX[le * LDH + q * 32 + i * 8]) = vh;
            }
        }
        __syncthreads();

        // MFMA: both halves accumulated from shared A-frags.
        f32x4 acc[2][4][2];
#pragma unroll
        for (int half = 0; half < 2; ++half)
#pragma unroll
            for (int rt = 0; rt < 4; ++rt)
#pragma unroll
                for (int c = 0; c < 2; ++c) acc[half][rt][c] = (f32x4){0.f, 0.f, 0.f, 0.f};

#pragma unroll
        for (int ks = 0; ks < 4; ++ks) {
#pragma unroll
            for (int rt = 0; rt < 4; ++rt) {
                f16x8 a = *(const f16x8*)(&sX[(rt * 16 + ln) * LDH + ks * 32 + kg * 8]);
#pragma unroll
                for (int half = 0; half < 2; ++half)
#pragma unroll
                    for (int c = 0; c < 2; ++c)
                        acc[half][rt][c] = __builtin_amdgcn_mfma_f32_16x16x32_f16(
                            a, bf[half][c][ks], acc[half][rt][c], 0, 0, 0);
            }
        }

        // Epilogue per half: bounce through sX, coalesced f16 stores.
#pragma unroll
        for (int half = 0; half < 2; ++half) {
            __syncthreads();
#pragma unroll
            for (int rt = 0; rt < 4; ++rt)
#pragma unroll
                for (int c = 0; c < 2; ++c) {
                    int col = w * 32 + c * 16 + ln;
#pragma unroll
                    for (int reg = 0; reg < 4; ++reg) {
                        int row = rt * 16 + kg * 4 + reg;   // C-layout [m89/m91]
                        sX[row * LDH + col] = (_Float16)acc[half][rt][c][reg];
                    }
                }
            __syncthreads();
            int n = n0 + le;
            if (n < N_NODES) {
                _Float16* dst = P + (size_t)n * 256 + half * 128 + q * 32;
                const _Float16* srcp = &sX[le * LDH + q * 32];
#pragma unroll
                for (int i = 0; i < 4; ++i)
                    *(f16x8*)(dst + i * 8) = *(const f16x8*)(srcp + i * 8);
            }
        }
    }
}

// k2: byte-identical to the proven 85us round-0 kernel. DO NOT TOUCH.
extern "C" __global__ __launch_bounds__(256, 3)
void k2_edge_mlp(const _Float16* __restrict__ P, const void* __restrict__ eiv,
                 const float* __restrict__ b1, const float* __restrict__ W2,
                 const float* __restrict__ b2, const float* __restrict__ W3,
                 const float* __restrict__ b3, float* __restrict__ out) {
    __shared__ __align__(16) _Float16 sH[2][64 * LDH];   // 34.8 KB
    __shared__ float sPart[2][4][64];                    // 2 KB
    __shared__ int sFlag;

    const int t = threadIdx.x;
    const int w = t >> 6, lane = t & 63;
    const int ln = lane & 15, kg = lane >> 4;
    const int row = t >> 2;          // staging row 0..63
    const int kc0 = (t & 3) * 4;     // staging k-chunk base (of 16 chunks/row)
    const float b3v = b3[0];
    const int stride = gridDim.x;

    if (t < 64) {
        unsigned v = ((const unsigned*)eiv)[2 * t + 1];
        unsigned long long bm = __ballot(v == 0u);
        if (t == 0) sFlag = (bm == ~0ull) ? 1 : 0;
    }

    f16x8 b1f[4];
#pragma unroll
    for (int i = 0; i < 4; ++i)
#pragma unroll
        for (int j = 0; j < 8; ++j) b1f[i][j] = (_Float16)b1[(kc0 + i) * 8 + j];

    float w3v[2], b2v[2];
#pragma unroll
    for (int c = 0; c < 2; ++c) {
        int col = w * 32 + c * 16 + ln;
        w3v[c] = W3[col]; b2v[c] = b2[col];
    }

    f16x8 bfw[2][4];
#pragma unroll
    for (int c = 0; c < 2; ++c) {
        const int n = w * 32 + c * 16 + ln;
#pragma unroll
        for (int ks = 0; ks < 4; ++ks) {
            f16x8 v;
#pragma unroll
            for (int j = 0; j < 8; ++j) {
                int k = ks * 32 + kg * 8 + j;
                v[j] = (_Float16)W2[k * 128 + n];
            }
            bfw[c][ks] = v;
        }
    }
    __syncthreads();
    const int mode64 = sFlag;

    const int tile0 = blockIdx.x;   // 768 <= NT2 always

    int se_nx, ge_nx;
    {
        int e = tile0 * 64 + row;
        if (mode64) {
            se_nx = (int)((const long long*)eiv)[e];
            ge_nx = (int)((const long long*)eiv)[N_EDGES + e];
        } else {
            se_nx = ((const int*)eiv)[e];
            ge_nx = ((const int*)eiv)[N_EDGES + e];
        }
    }
    {
        const _Float16* pa = P + (size_t)se_nx * 256 + kc0 * 8;
        const _Float16* pb = P + (size_t)ge_nx * 256 + 128 + kc0 * 8;
        f16x8 Ga[4], Gb[4];
#pragma unroll
        for (int i = 0; i < 4; ++i) {
            Ga[i] = *(const f16x8*)(pa + i * 8);
            Gb[i] = *(const f16x8*)(pb + i * 8);
        }
#pragma unroll
        for (int i = 0; i < 4; ++i) {
            f16x8 s = Ga[i] + Gb[i] + b1f[i];   // packed f16 adds
            f16x8 vh;
#pragma unroll
            for (int j = 0; j < 8; ++j) {
                _Float16 sv = s[j];
                vh[j] = (sv > (_Float16)0) ? sv
                        : (_Float16)(__expf((float)sv) - 1.0f);
            }
            *(f16x8*)(&sH[0][row * LDH + (kc0 + i) * 8]) = vh;
        }
    }
    {
        int t1 = tile0 + stride;
        int t1c = (t1 < NT2) ? t1 : tile0;
        int e = t1c * 64 + row;
        if (mode64) {
            se_nx = (int)((const long long*)eiv)[e];
            ge_nx = (int)((const long long*)eiv)[N_EDGES + e];
        } else {
            se_nx = ((const int*)eiv)[e];
            ge_nx = ((const int*)eiv)[N_EDGES + e];
        }
    }
    __syncthreads();   // sH[0] ready

    int p = 0;
    int prevE0 = -1;
    for (int tile = tile0; tile < NT2; tile += stride) {
        const int nt = tile + stride;
        const int ntc = (nt < NT2) ? nt : tile;

        // (1) Issue gathers for tile nt.
        const _Float16* pa = P + (size_t)se_nx * 256 + kc0 * 8;
        const _Float16* pb = P + (size_t)ge_nx * 256 + 128 + kc0 * 8;
        f16x8 Ga[4], Gb[4];
#pragma unroll
        for (int i = 0; i < 4; ++i) {
            Ga[i] = *(const f16x8*)(pa + i * 8);
            Gb[i] = *(const f16x8*)(pb + i * 8);
        }

        // (1b) Indices for tile nt+stride.
        {
            int n2 = nt + stride;
            int n2c = (n2 < NT2) ? n2 : ntc;
            int e = n2c * 64 + row;
            if (mode64) {
                se_nx = (int)((const long long*)eiv)[e];
                ge_nx = (int)((const long long*)eiv)[N_EDGES + e];
            } else {
                se_nx = ((const int*)eiv)[e];
                ge_nx = ((const int*)eiv)[N_EDGES + e];
            }
        }

        // (2) Out-write for the previous tile.
        if (prevE0 >= 0 && t < 64)
            out[prevE0 + t] = sPart[p ^ 1][0][t] + sPart[p ^ 1][1][t] +
                              sPart[p ^ 1][2][t] + sPart[p ^ 1][3][t] + b3v;

        // (3) MFMA on sH[p] + fused layer 3 -> sPart[p].
        f32x4 acc[4][2];
#pragma unroll
        for (int rt = 0; rt < 4; ++rt)
#pragma unroll
            for (int c = 0; c < 2; ++c) acc[rt][c] = (f32x4){0.f, 0.f, 0.f, 0.f};

#pragma unroll
        for (int ks = 0; ks < 4; ++ks) {
#pragma unroll
            for (int rt = 0; rt < 4; ++rt) {
                f16x8 a = *(const f16x8*)(&sH[p][(rt * 16 + ln) * LDH + ks * 32 + kg * 8]);
#pragma unroll
                for (int c = 0; c < 2; ++c)
                    acc[rt][c] = __builtin_amdgcn_mfma_f32_16x16x32_f16(a, bfw[c][ks], acc[rt][c], 0, 0, 0);
            }
        }

#pragma unroll
        for (int rt = 0; rt < 4; ++rt) {
            float pr[4] = {0.f, 0.f, 0.f, 0.f};
#pragma unroll
            for (int c = 0; c < 2; ++c) {
#pragma unroll
                for (int reg = 0; reg < 4; ++reg)
                    pr[reg] += elu_f(acc[rt][c][reg] + b2v[c]) * w3v[c];
            }
#pragma unroll
            for (int m = 1; m < 16; m <<= 1)
#pragma unroll
                for (int reg = 0; reg < 4; ++reg) pr[reg] += __shfl_xor(pr[reg], m, 64);
            if (ln == 0) {
#pragma unroll
                for (int reg = 0; reg < 4; ++reg)
                    sPart[p][w][rt * 16 + kg * 4 + reg] = pr[reg];
            }
        }

        // (4) Combine gathered tile nt -> sH[p^1] (packed f16 math).
#pragma unroll
        for (int i = 0; i < 4; ++i) {
            f16x8 s = Ga[i] + Gb[i] + b1f[i];   // v_pk_add_f16
            f16x8 vh;
#pragma unroll
            for (int j = 0; j < 8; ++j) {
                _Float16 sv = s[j];
                vh[j] = (sv > (_Float16)0) ? sv
                        : (_Float16)(__expf((float)sv) - 1.0f);
            }
            *(f16x8*)(&sH[p ^ 1][row * LDH + (kc0 + i) * 8]) = vh;
        }

        prevE0 = tile * 64;
        __syncthreads();   // the ONLY per-tile barrier
        p ^= 1;
    }

    if (prevE0 >= 0 && t < 64)
        out[prevE0 + t] = sPart[p ^ 1][0][t] + sPart[p ^ 1][1][t] +
                          sPart[p ^ 1][2][t] + sPart[p ^ 1][3][t] + b3v;
}

extern "C" void kernel_launch(void* const* d_in, const int* in_sizes, int n_in,
                              void* d_out, int out_size, void* d_ws, size_t ws_size,
                              hipStream_t stream) {
    const float* x  = (const float*)d_in[0];
    const void*  ei = d_in[1];
    const float* W1 = (const float*)d_in[2];
    const float* b1 = (const float*)d_in[3];
    const float* W2 = (const float*)d_in[4];
    const float* b2 = (const float*)d_in[5];
    const float* W3 = (const float*)d_in[6];
    const float* b3 = (const float*)d_in[7];
    float* out = (float*)d_out;

    _Float16* P   = (_Float16*)((char*)d_ws + 256);        // 51.2 MB
    _Float16* W1f = P + (size_t)N_NODES * 256;             // 64 KB

    k0_w1f<<<16, 256, 0, stream>>>(W1, W1f);
    k1_node_linear<<<768, 256, 0, stream>>>(x, W1f, P);
    k2_edge_mlp<<<768, 256, 0, stream>>>(P, ei, b1, W2, b2, W3, b3, out);
}